// Round 7
// baseline (277.307 us; speedup 1.0000x reference)
//
#include <hip/hip_runtime.h>

#define D 128

typedef __attribute__((ext_vector_type(8))) short short8;
typedef __attribute__((ext_vector_type(4))) float f32x4;

static __device__ __forceinline__ unsigned short f2bf(float f) {
    union { float f; unsigned u; } v; v.f = f;
    unsigned r = v.u + 0x7FFF + ((v.u >> 16) & 1);   // RNE
    return (unsigned short)(r >> 16);
}

static __device__ __forceinline__ float2 bfpair2f(unsigned p) {
    union { unsigned u; float f; } a, b;
    a.u = (p & 0xFFFFu) << 16;
    b.u = p & 0xFFFF0000u;
    return make_float2(a.f, b.f);
}

// ---------------- x -> bf16 row-major ----------------
__global__ __launch_bounds__(256) void xprep_kernel(
    const float4* __restrict__ x4, uint2* __restrict__ xh, int total)
{
    int i = blockIdx.x * 256 + threadIdx.x;
    if (i >= total) return;
    float4 v = x4[i];
    uint2 o;
    o.x = (unsigned)f2bf(v.x) | ((unsigned)f2bf(v.y) << 16);
    o.y = (unsigned)f2bf(v.z) | ((unsigned)f2bf(v.w) << 16);
    xh[i] = o;
}

// -------- linked-list build: 4 chains per dst; rec[e] = {src, prev} --------
__global__ __launch_bounds__(256) void link_build_kernel(
    const int* __restrict__ ei, int* __restrict__ head,
    int2* __restrict__ rec, int E)
{
    int e = blockIdx.x * 256 + threadIdx.x;
    if (e >= E) return;
    int src = ei[e];
    int dst = ei[E + e];
    int old = atomicExch(&head[dst * 4 + (e & 3)], e);
    rec[e] = make_int2(src, old);
}

// -------- gather (bf16): h0[n] = bf16((1+eps)*x[n] + sum x[src]) --------
// 4 simultaneous chains per node; rec packs src+next in one cache line.
__global__ __launch_bounds__(256) void gather_kernel(
    const unsigned* __restrict__ xh, const int* __restrict__ head,
    const int2* __restrict__ rec, const float* __restrict__ epsp,
    unsigned* __restrict__ h0, int N)
{
    int gtid = blockIdx.x * 256 + threadIdx.x;
    int node = gtid >> 6;
    int lane = gtid & 63;
    if (node >= N) return;

    float epsv = 1.0f + __ldg(epsp);
    float2 xv = bfpair2f(xh[(size_t)node * 64 + lane]);
    float ax = epsv * xv.x, ay = epsv * xv.y;

    int e0 = head[node * 4 + 0];
    int e1 = head[node * 4 + 1];
    int e2 = head[node * 4 + 2];
    int e3 = head[node * 4 + 3];
    for (;;) {
        bool b0 = e0 >= 0, b1 = e1 >= 0, b2 = e2 >= 0, b3 = e3 >= 0;
        if (!(b0 || b1 || b2 || b3)) break;
        int2 r0, r1, r2, r3;
        if (b0) r0 = rec[e0];
        if (b1) r1 = rec[e1];
        if (b2) r2 = rec[e2];
        if (b3) r3 = rec[e3];
        if (b0) {
            float2 v = bfpair2f(xh[(size_t)r0.x * 64 + lane]);
            ax += v.x; ay += v.y; e0 = r0.y;
        }
        if (b1) {
            float2 v = bfpair2f(xh[(size_t)r1.x * 64 + lane]);
            ax += v.x; ay += v.y; e1 = r1.y;
        }
        if (b2) {
            float2 v = bfpair2f(xh[(size_t)r2.x * 64 + lane]);
            ax += v.x; ay += v.y; e2 = r2.y;
        }
        if (b3) {
            float2 v = bfpair2f(xh[(size_t)r3.x * 64 + lane]);
            ax += v.x; ay += v.y; e3 = r3.y;
        }
    }
    h0[(size_t)node * 64 + lane] =
        (unsigned)f2bf(ax) | ((unsigned)f2bf(ay) << 16);
}

// ---------------- W prep: fp32 [k][n] -> bf16 fragment-ordered ----------------
__global__ __launch_bounds__(256) void wprep_kernel(
    const float* __restrict__ W1, const float* __restrict__ W2,
    unsigned short* __restrict__ Wf1, unsigned short* __restrict__ Wf2)
{
    int idx = blockIdx.x * 256 + threadIdx.x;   // 0..32767
    const float* W = (idx < 16384) ? W1 : W2;
    unsigned short* Wf = (idx < 16384) ? Wf1 : Wf2;
    int e = idx & 16383;
    int j = e & 7, lane = (e >> 3) & 63, ckk = e >> 9;
    int ct = ckk & 7, kk = ckk >> 3;
    int k = kk * 32 + (lane >> 4) * 8 + j;
    int n = ct * 16 + (lane & 15);
    Wf[e] = f2bf(W[k * 128 + n]);
}

// ---------------- MFMA GEMM + BN-stat accumulation (bf16 in/out) ----------------
// mode 0: A = a_bf rows as-is
// mode 1: A = bf16(relu(a_bf * s[k] + t[k])), s/t computed in-kernel from
//         stat_in (sum @0, sumsq @128) + gamma/beta (fused BN finalize)
// zout: bf16. Stats accumulated from fp32 accumulators (pre-rounding).
__global__ __launch_bounds__(256) void gemm_bn_mfma_kernel(
    const unsigned short* __restrict__ a_bf,
    const float* __restrict__ stat_in, const float* __restrict__ gamma,
    const float* __restrict__ beta, float invN,
    const unsigned short* __restrict__ Wf, const float* __restrict__ bias,
    unsigned short* __restrict__ zout,
    float* __restrict__ stat_sum, float* __restrict__ stat_sq,
    int N, int mode)
{
    __shared__ unsigned short Wl[16384];   // 32 KB, fragment-ordered
    __shared__ float part[1024];
    __shared__ float scf[128], shf[128];

    int tid = threadIdx.x;
    {
        float4* dst = (float4*)Wl;
        const float4* srcp = (const float4*)Wf;
        #pragma unroll
        for (int i = 0; i < 8; ++i) dst[tid + i * 256] = srcp[tid + i * 256];
    }
    if (mode == 1 && tid < 128) {          // fused BN finalize for the input
        float mean = stat_in[tid] * invN;
        float var  = stat_in[128 + tid] * invN - mean * mean;
        float sv = gamma[tid] * rsqrtf(var + 1e-5f);
        scf[tid] = sv;
        shf[tid] = fmaf(-mean, sv, beta[tid]);
    }
    __syncthreads();

    int w = tid >> 6, lane = tid & 63, q = lane >> 4, n16 = lane & 15;
    int rowb = blockIdx.x * 64 + w * 16;
    int m = rowb + n16;
    int mc = (m < N) ? m : (N - 1);
    const unsigned short* arow = a_bf + (size_t)mc * D;

    f32x4 acc[8];
    #pragma unroll
    for (int ct = 0; ct < 8; ++ct) acc[ct] = (f32x4){0.f, 0.f, 0.f, 0.f};

    #pragma unroll
    for (int kk = 0; kk < 4; ++kk) {
        int c = kk * 32 + q * 8;
        short8 af;
        if (mode == 0) {
            af = *(const short8*)(arow + c);
        } else {
            uint4 rw = *(const uint4*)(arow + c);
            float2 p0 = bfpair2f(rw.x), p1 = bfpair2f(rw.y);
            float2 p2 = bfpair2f(rw.z), p3 = bfpair2f(rw.w);
            p0.x = fmaxf(fmaf(p0.x, scf[c + 0], shf[c + 0]), 0.f);
            p0.y = fmaxf(fmaf(p0.y, scf[c + 1], shf[c + 1]), 0.f);
            p1.x = fmaxf(fmaf(p1.x, scf[c + 2], shf[c + 2]), 0.f);
            p1.y = fmaxf(fmaf(p1.y, scf[c + 3], shf[c + 3]), 0.f);
            p2.x = fmaxf(fmaf(p2.x, scf[c + 4], shf[c + 4]), 0.f);
            p2.y = fmaxf(fmaf(p2.y, scf[c + 5], shf[c + 5]), 0.f);
            p3.x = fmaxf(fmaf(p3.x, scf[c + 6], shf[c + 6]), 0.f);
            p3.y = fmaxf(fmaf(p3.y, scf[c + 7], shf[c + 7]), 0.f);
            af[0] = (short)f2bf(p0.x); af[1] = (short)f2bf(p0.y);
            af[2] = (short)f2bf(p1.x); af[3] = (short)f2bf(p1.y);
            af[4] = (short)f2bf(p2.x); af[5] = (short)f2bf(p2.y);
            af[6] = (short)f2bf(p3.x); af[7] = (short)f2bf(p3.y);
        }
        #pragma unroll
        for (int ct = 0; ct < 8; ++ct) {
            short8 bf = *(const short8*)&Wl[(((kk * 8 + ct) * 64) + lane) * 8];
            acc[ct] = __builtin_amdgcn_mfma_f32_16x16x32_bf16(af, bf, acc[ct], 0, 0, 0);
        }
    }

    // epilogue: bias add, bf16 store, per-column stats (from fp32 values)
    #pragma unroll
    for (int ct = 0; ct < 8; ++ct) {
        int col = ct * 16 + n16;
        float bv = __ldg(bias + col);
        float s = 0.f, qs = 0.f;
        #pragma unroll
        for (int reg = 0; reg < 4; ++reg) {
            int row = rowb + q * 4 + reg;
            float v = acc[ct][reg] + bv;
            if (row < N) {
                zout[(size_t)row * D + col] = f2bf(v);
                s += v;
                qs = fmaf(v, v, qs);
            }
        }
        s  += __shfl_xor(s, 16, 64);
        s  += __shfl_xor(s, 32, 64);
        qs += __shfl_xor(qs, 16, 64);
        qs += __shfl_xor(qs, 32, 64);
        if (lane < 16) {
            part[w * 128 + col] = s;
            part[512 + w * 128 + col] = qs;
        }
    }
    __syncthreads();

    if (tid < 128) {
        float s  = part[tid] + part[128 + tid] + part[256 + tid] + part[384 + tid];
        float qq = part[512 + tid] + part[640 + tid] + part[768 + tid] + part[896 + tid];
        atomicAdd(&stat_sum[tid], s);
        atomicAdd(&stat_sq[tid], qq);
    }
}

// ------- final BN + ReLU (fused BN2 finalize): bf16 z2 -> fp32 out -------
__global__ __launch_bounds__(256) void bn_relu_kernel(
    const uint2* __restrict__ z2, float4* __restrict__ out,
    const float* __restrict__ stat2, const float* __restrict__ gamma,
    const float* __restrict__ beta, float invN, int total4)
{
    __shared__ float sf[128], tf[128];
    int tid = threadIdx.x;
    if (tid < 128) {
        float mean = stat2[tid] * invN;
        float var  = stat2[128 + tid] * invN - mean * mean;
        float sv = gamma[tid] * rsqrtf(var + 1e-5f);
        sf[tid] = sv;
        tf[tid] = fmaf(-mean, sv, beta[tid]);
    }
    __syncthreads();

    int i = blockIdx.x * 256 + tid;
    if (i >= total4) return;
    uint2 zp = z2[i];
    float2 v01 = bfpair2f(zp.x);
    float2 v23 = bfpair2f(zp.y);
    int c = (i & 31) * 4;
    float4 o;
    o.x = fmaxf(fmaf(v01.x, sf[c + 0], tf[c + 0]), 0.f);
    o.y = fmaxf(fmaf(v01.y, sf[c + 1], tf[c + 1]), 0.f);
    o.z = fmaxf(fmaf(v23.x, sf[c + 2], tf[c + 2]), 0.f);
    o.w = fmaxf(fmaf(v23.y, sf[c + 3], tf[c + 3]), 0.f);
    out[i] = o;
}

extern "C" void kernel_launch(void* const* d_in, const int* in_sizes, int n_in,
                              void* d_out, int out_size, void* d_ws, size_t ws_size,
                              hipStream_t stream)
{
    const float* x   = (const float*)d_in[0];
    const int*   ei  = (const int*)d_in[1];
    const float* eps = (const float*)d_in[2];
    const float* W1  = (const float*)d_in[3];
    const float* b1  = (const float*)d_in[4];
    const float* g1  = (const float*)d_in[5];
    const float* be1 = (const float*)d_in[6];
    const float* W2  = (const float*)d_in[7];
    const float* b2  = (const float*)d_in[8];
    const float* g2  = (const float*)d_in[9];
    const float* be2 = (const float*)d_in[10];

    int N = in_sizes[0] / D;       // 50000
    int E = in_sizes[1] / 2;       // 800000
    size_t ND = (size_t)N * D;

    // workspace layout (peak ~26.5 MB, less than prior rounds):
    //   [0 : ND) ushort      : xh (phase 1) -> z1 bf16 (phases 2-3)
    //   [ND : 2*ND) ushort   : rec int2 (phase 1, 6.4 MB) -> z2 bf16 (phases 3-4)
    //   then stats (512 f), head (4N ints), Wf1/Wf2 (16384 ushorts each)
    // h0 (bf16, phase 1-2) lives in d_out; overwritten by the final fp32 output.
    unsigned short* xh  = (unsigned short*)d_ws;
    unsigned short* z1  = xh;            // reuses xh region (xh dead after gather)
    int2* rec           = (int2*)(xh + ND);
    unsigned short* z2  = xh + ND;       // reuses rec region (rec dead after gather)
    float* stats        = (float*)(xh + 2 * ND);
    int* head           = (int*)(stats + 512);
    unsigned short* Wf1 = (unsigned short*)(head + 4 * (size_t)N);
    unsigned short* Wf2 = Wf1 + 16384;

    float* sum1 = stats + 0,   *sq1 = stats + 128;
    float* sum2 = stats + 256, *sq2 = stats + 384;
    unsigned short* h0 = (unsigned short*)d_out;

    hipMemsetAsync(stats, 0, 512 * sizeof(float), stream);
    hipMemsetAsync(head, 0xFF, 4 * (size_t)N * sizeof(int), stream);  // -1

    int eblocks = (E + 255) / 256;
    wprep_kernel<<<128, 256, 0, stream>>>(W1, W2, Wf1, Wf2);
    xprep_kernel<<<(N * 32 + 255) / 256, 256, 0, stream>>>(
        (const float4*)x, (uint2*)xh, N * 32);
    link_build_kernel<<<eblocks, 256, 0, stream>>>(ei, head, rec, E);
    gather_kernel<<<(N * 64 + 255) / 256, 256, 0, stream>>>(
        (const unsigned*)xh, head, rec, eps, (unsigned*)h0, N);

    int gblocks = (N + 63) / 64;
    gemm_bn_mfma_kernel<<<gblocks, 256, 0, stream>>>(
        h0, nullptr, nullptr, nullptr, 0.f,
        Wf1, b1, z1, sum1, sq1, N, 0);
    gemm_bn_mfma_kernel<<<gblocks, 256, 0, stream>>>(
        z1, sum1, g1, be1, 1.0f / N,
        Wf2, b2, z2, sum2, sq2, N, 1);
    bn_relu_kernel<<<(N * 32 + 255) / 256, 256, 0, stream>>>(
        (const uint2*)z2, (float4*)d_out, sum2, g2, be2, 1.0f / N, N * 32);
}

// Round 8
// 264.374 us; speedup vs baseline: 1.0489x; 1.0489x over previous
//
#include <hip/hip_runtime.h>

#define D 128

typedef __attribute__((ext_vector_type(8))) short short8;
typedef __attribute__((ext_vector_type(4))) float f32x4;

static __device__ __forceinline__ unsigned short f2bf(float f) {
    union { float f; unsigned u; } v; v.f = f;
    unsigned r = v.u + 0x7FFF + ((v.u >> 16) & 1);   // RNE
    return (unsigned short)(r >> 16);
}

static __device__ __forceinline__ float2 bfpair2f(unsigned p) {
    union { unsigned u; float f; } a, b;
    a.u = (p & 0xFFFFu) << 16;
    b.u = p & 0xFFFF0000u;
    return make_float2(a.f, b.f);
}

// ------------- fused prep: x -> bf16 rows, W1/W2 -> bf16 fragments -------------
__global__ __launch_bounds__(256) void prep_kernel(
    const float4* __restrict__ x4, uint2* __restrict__ xh, int xtotal,
    const float* __restrict__ W1, const float* __restrict__ W2,
    unsigned short* __restrict__ Wf1, unsigned short* __restrict__ Wf2,
    int xblocks)
{
    if (blockIdx.x < (unsigned)xblocks) {
        int i = blockIdx.x * 256 + threadIdx.x;
        if (i >= xtotal) return;
        float4 v = x4[i];
        uint2 o;
        o.x = (unsigned)f2bf(v.x) | ((unsigned)f2bf(v.y) << 16);
        o.y = (unsigned)f2bf(v.z) | ((unsigned)f2bf(v.w) << 16);
        xh[i] = o;
    } else {
        int idx = (blockIdx.x - xblocks) * 256 + threadIdx.x;   // 0..32767
        const float* W = (idx < 16384) ? W1 : W2;
        unsigned short* Wf = (idx < 16384) ? Wf1 : Wf2;
        int e = idx & 16383;
        int j = e & 7, lane = (e >> 3) & 63, ckk = e >> 9;
        int ct = ckk & 7, kk = ckk >> 3;
        int k = kk * 32 + (lane >> 4) * 8 + j;
        int n = ct * 16 + (lane & 15);
        Wf[e] = f2bf(W[k * 128 + n]);
    }
}

// -------- linked-list build: 2 chains per dst; rec[e] = {src, prev} --------
__global__ __launch_bounds__(256) void link_build_kernel(
    const int* __restrict__ ei, int* __restrict__ head,
    int2* __restrict__ rec, int E)
{
    int e = blockIdx.x * 256 + threadIdx.x;
    if (e >= E) return;
    int src = ei[e];
    int dst = ei[E + e];
    int old = atomicExch(&head[dst * 2 + (e & 1)], e);
    rec[e] = make_int2(src, old);
}

// -------- gather: 4 nodes/wave x 2 chains = 8 streams, branchless --------
__global__ __launch_bounds__(256) void gather_kernel(
    const unsigned* __restrict__ xh, const int* __restrict__ head,
    const int2* __restrict__ rec, const float* __restrict__ epsp,
    unsigned* __restrict__ h0, int N)
{
    int wave = (blockIdx.x * 256 + threadIdx.x) >> 6;
    int lane = threadIdx.x & 63;
    int n0 = wave * 4;
    if (n0 >= N) return;

    float epsv = 1.0f + __ldg(epsp);

    float ax[4], ay[4];
    int e[8];
    #pragma unroll
    for (int i = 0; i < 4; ++i) {
        int node = n0 + i;
        int ok = (node < N);
        int nc = ok ? node : 0;
        float2 xv = bfpair2f(xh[(size_t)nc * 64 + lane]);
        ax[i] = epsv * xv.x; ay[i] = epsv * xv.y;
        e[2 * i]     = ok ? head[nc * 2]     : -1;
        e[2 * i + 1] = ok ? head[nc * 2 + 1] : -1;
    }

    for (;;) {
        bool any = false;
        #pragma unroll
        for (int s = 0; s < 8; ++s) any |= (e[s] >= 0);
        if (!any) break;

        int2 r[8];
        #pragma unroll
        for (int s = 0; s < 8; ++s)
            r[s] = rec[e[s] >= 0 ? e[s] : 0];          // clamped, unconditional

        unsigned pv[8];
        #pragma unroll
        for (int s = 0; s < 8; ++s)
            pv[s] = xh[(size_t)(e[s] >= 0 ? r[s].x : 0) * 64 + lane];

        #pragma unroll
        for (int s = 0; s < 8; ++s) {
            float m = (e[s] >= 0) ? 1.0f : 0.0f;       // branchless mask
            float2 v = bfpair2f(pv[s]);
            int i = s >> 1;
            ax[i] = fmaf(m, v.x, ax[i]);
            ay[i] = fmaf(m, v.y, ay[i]);
            e[s] = (e[s] >= 0) ? r[s].y : -1;
        }
    }

    #pragma unroll
    for (int i = 0; i < 4; ++i) {
        int node = n0 + i;
        if (node < N)
            h0[(size_t)node * 64 + lane] =
                (unsigned)f2bf(ax[i]) | ((unsigned)f2bf(ay[i]) << 16);
    }
}

// ---------------- MFMA GEMM + BN-stat accumulation (bf16 in/out) ----------------
// mode 0: A = a_bf rows as-is
// mode 1: A = bf16(relu(a_bf * s[k] + t[k])), s/t computed in-kernel from
//         stat_in (sum @0, sumsq @128) + gamma/beta (fused BN finalize)
__global__ __launch_bounds__(256) void gemm_bn_mfma_kernel(
    const unsigned short* __restrict__ a_bf,
    const float* __restrict__ stat_in, const float* __restrict__ gamma,
    const float* __restrict__ beta, float invN,
    const unsigned short* __restrict__ Wf, const float* __restrict__ bias,
    unsigned short* __restrict__ zout,
    float* __restrict__ stat_sum, float* __restrict__ stat_sq,
    int N, int mode)
{
    __shared__ unsigned short Wl[16384];   // 32 KB, fragment-ordered
    __shared__ float part[1024];
    __shared__ float scf[128], shf[128];

    int tid = threadIdx.x;
    {
        float4* dst = (float4*)Wl;
        const float4* srcp = (const float4*)Wf;
        #pragma unroll
        for (int i = 0; i < 8; ++i) dst[tid + i * 256] = srcp[tid + i * 256];
    }
    if (mode == 1 && tid < 128) {          // fused BN finalize for the input
        float mean = stat_in[tid] * invN;
        float var  = stat_in[128 + tid] * invN - mean * mean;
        float sv = gamma[tid] * rsqrtf(var + 1e-5f);
        scf[tid] = sv;
        shf[tid] = fmaf(-mean, sv, beta[tid]);
    }
    __syncthreads();

    int w = tid >> 6, lane = tid & 63, q = lane >> 4, n16 = lane & 15;
    int rowb = blockIdx.x * 64 + w * 16;
    int m = rowb + n16;
    int mc = (m < N) ? m : (N - 1);
    const unsigned short* arow = a_bf + (size_t)mc * D;

    f32x4 acc[8];
    #pragma unroll
    for (int ct = 0; ct < 8; ++ct) acc[ct] = (f32x4){0.f, 0.f, 0.f, 0.f};

    #pragma unroll
    for (int kk = 0; kk < 4; ++kk) {
        int c = kk * 32 + q * 8;
        short8 af;
        if (mode == 0) {
            af = *(const short8*)(arow + c);
        } else {
            uint4 rw = *(const uint4*)(arow + c);
            float2 p0 = bfpair2f(rw.x), p1 = bfpair2f(rw.y);
            float2 p2 = bfpair2f(rw.z), p3 = bfpair2f(rw.w);
            p0.x = fmaxf(fmaf(p0.x, scf[c + 0], shf[c + 0]), 0.f);
            p0.y = fmaxf(fmaf(p0.y, scf[c + 1], shf[c + 1]), 0.f);
            p1.x = fmaxf(fmaf(p1.x, scf[c + 2], shf[c + 2]), 0.f);
            p1.y = fmaxf(fmaf(p1.y, scf[c + 3], shf[c + 3]), 0.f);
            p2.x = fmaxf(fmaf(p2.x, scf[c + 4], shf[c + 4]), 0.f);
            p2.y = fmaxf(fmaf(p2.y, scf[c + 5], shf[c + 5]), 0.f);
            p3.x = fmaxf(fmaf(p3.x, scf[c + 6], shf[c + 6]), 0.f);
            p3.y = fmaxf(fmaf(p3.y, scf[c + 7], shf[c + 7]), 0.f);
            af[0] = (short)f2bf(p0.x); af[1] = (short)f2bf(p0.y);
            af[2] = (short)f2bf(p1.x); af[3] = (short)f2bf(p1.y);
            af[4] = (short)f2bf(p2.x); af[5] = (short)f2bf(p2.y);
            af[6] = (short)f2bf(p3.x); af[7] = (short)f2bf(p3.y);
        }
        #pragma unroll
        for (int ct = 0; ct < 8; ++ct) {
            short8 bf = *(const short8*)&Wl[(((kk * 8 + ct) * 64) + lane) * 8];
            acc[ct] = __builtin_amdgcn_mfma_f32_16x16x32_bf16(af, bf, acc[ct], 0, 0, 0);
        }
    }

    // epilogue: bias add, bf16 store, per-column stats (from fp32 values)
    #pragma unroll
    for (int ct = 0; ct < 8; ++ct) {
        int col = ct * 16 + n16;
        float bv = __ldg(bias + col);
        float s = 0.f, qs = 0.f;
        #pragma unroll
        for (int reg = 0; reg < 4; ++reg) {
            int row = rowb + q * 4 + reg;
            float v = acc[ct][reg] + bv;
            if (row < N) {
                zout[(size_t)row * D + col] = f2bf(v);
                s += v;
                qs = fmaf(v, v, qs);
            }
        }
        s  += __shfl_xor(s, 16, 64);
        s  += __shfl_xor(s, 32, 64);
        qs += __shfl_xor(qs, 16, 64);
        qs += __shfl_xor(qs, 32, 64);
        if (lane < 16) {
            part[w * 128 + col] = s;
            part[512 + w * 128 + col] = qs;
        }
    }
    __syncthreads();

    if (tid < 128) {
        float s  = part[tid] + part[128 + tid] + part[256 + tid] + part[384 + tid];
        float qq = part[512 + tid] + part[640 + tid] + part[768 + tid] + part[896 + tid];
        atomicAdd(&stat_sum[tid], s);
        atomicAdd(&stat_sq[tid], qq);
    }
}

// ------- final BN + ReLU (fused BN2 finalize): bf16 z2 -> fp32 out -------
__global__ __launch_bounds__(256) void bn_relu_kernel(
    const uint2* __restrict__ z2, float4* __restrict__ out,
    const float* __restrict__ stat2, const float* __restrict__ gamma,
    const float* __restrict__ beta, float invN, int total4)
{
    __shared__ float sf[128], tf[128];
    int tid = threadIdx.x;
    if (tid < 128) {
        float mean = stat2[tid] * invN;
        float var  = stat2[128 + tid] * invN - mean * mean;
        float sv = gamma[tid] * rsqrtf(var + 1e-5f);
        sf[tid] = sv;
        tf[tid] = fmaf(-mean, sv, beta[tid]);
    }
    __syncthreads();

    int i = blockIdx.x * 256 + tid;
    if (i >= total4) return;
    uint2 zp = z2[i];
    float2 v01 = bfpair2f(zp.x);
    float2 v23 = bfpair2f(zp.y);
    int c = (i & 31) * 4;
    float4 o;
    o.x = fmaxf(fmaf(v01.x, sf[c + 0], tf[c + 0]), 0.f);
    o.y = fmaxf(fmaf(v01.y, sf[c + 1], tf[c + 1]), 0.f);
    o.z = fmaxf(fmaf(v23.x, sf[c + 2], tf[c + 2]), 0.f);
    o.w = fmaxf(fmaf(v23.y, sf[c + 3], tf[c + 3]), 0.f);
    out[i] = o;
}

extern "C" void kernel_launch(void* const* d_in, const int* in_sizes, int n_in,
                              void* d_out, int out_size, void* d_ws, size_t ws_size,
                              hipStream_t stream)
{
    const float* x   = (const float*)d_in[0];
    const int*   ei  = (const int*)d_in[1];
    const float* eps = (const float*)d_in[2];
    const float* W1  = (const float*)d_in[3];
    const float* b1  = (const float*)d_in[4];
    const float* g1  = (const float*)d_in[5];
    const float* be1 = (const float*)d_in[6];
    const float* W2  = (const float*)d_in[7];
    const float* b2  = (const float*)d_in[8];
    const float* g2  = (const float*)d_in[9];
    const float* be2 = (const float*)d_in[10];

    int N = in_sizes[0] / D;       // 50000
    int E = in_sizes[1] / 2;       // 800000
    size_t ND = (size_t)N * D;

    // workspace layout:
    //   [0 : ND) ushort      : xh (phase 1) -> z1 bf16 (phases 2-3)
    //   [ND : 2*ND) ushort   : rec int2 (phase 1) -> z2 bf16 (phases 3-4)
    //   then stats (512 f), head (2N ints), Wf1/Wf2 (16384 ushorts each)
    // h0 (bf16) lives in d_out; overwritten by the final fp32 output.
    unsigned short* xh  = (unsigned short*)d_ws;
    unsigned short* z1  = xh;            // reuses xh region (xh dead after gather)
    int2* rec           = (int2*)(xh + ND);
    unsigned short* z2  = xh + ND;       // reuses rec region (rec dead after gather)
    float* stats        = (float*)(xh + 2 * ND);
    int* head           = (int*)(stats + 512);
    unsigned short* Wf1 = (unsigned short*)(head + 2 * (size_t)N);
    unsigned short* Wf2 = Wf1 + 16384;

    float* sum1 = stats + 0,   *sq1 = stats + 128;
    float* sum2 = stats + 256, *sq2 = stats + 384;
    unsigned short* h0 = (unsigned short*)d_out;

    hipMemsetAsync(stats, 0, 512 * sizeof(float), stream);
    hipMemsetAsync(head, 0xFF, 2 * (size_t)N * sizeof(int), stream);  // -1

    int eblocks = (E + 255) / 256;
    int xtotal = N * 32;                      // float4 groups in x
    int xblocks = (xtotal + 255) / 256;
    prep_kernel<<<xblocks + 128, 256, 0, stream>>>(
        (const float4*)x, (uint2*)xh, xtotal, W1, W2, Wf1, Wf2, xblocks);
    link_build_kernel<<<eblocks, 256, 0, stream>>>(ei, head, rec, E);
    int gwaves = (N + 3) / 4;
    gather_kernel<<<(gwaves * 64 + 255) / 256, 256, 0, stream>>>(
        (const unsigned*)xh, head, rec, eps, (unsigned*)h0, N);

    int gblocks = (N + 63) / 64;
    gemm_bn_mfma_kernel<<<gblocks, 256, 0, stream>>>(
        h0, nullptr, nullptr, nullptr, 0.f,
        Wf1, b1, z1, sum1, sq1, N, 0);
    gemm_bn_mfma_kernel<<<gblocks, 256, 0, stream>>>(
        z1, sum1, g1, be1, 1.0f / N,
        Wf2, b2, z2, sum2, sq2, N, 1);
    bn_relu_kernel<<<(N * 32 + 255) / 256, 256, 0, stream>>>(
        (const uint2*)z2, (float4*)d_out, sum2, g2, be2, 1.0f / N, N * 32);
}

// Round 9
// 231.485 us; speedup vs baseline: 1.1980x; 1.1421x over previous
//
#include <hip/hip_runtime.h>

#define D 128
#define FB 4096      // edges per hist/fill block
#define GCAP 1024    // src-list capacity per 32-dst gather block

typedef __attribute__((ext_vector_type(8))) short short8;
typedef __attribute__((ext_vector_type(4))) float f32x4;

static __device__ __forceinline__ unsigned short f2bf(float f) {
    union { float f; unsigned u; } v; v.f = f;
    unsigned r = v.u + 0x7FFF + ((v.u >> 16) & 1);   // RNE
    return (unsigned short)(r >> 16);
}

static __device__ __forceinline__ float2 bfpair2f(unsigned p) {
    union { unsigned u; float f; } a, b;
    a.u = (p & 0xFFFFu) << 16;
    b.u = p & 0xFFFF0000u;
    return make_float2(a.f, b.f);
}

// ------------- fused prep: x -> bf16 rows, W1/W2 -> bf16 fragments -------------
__global__ __launch_bounds__(256) void prep_kernel(
    const float4* __restrict__ x4, uint2* __restrict__ xh, int xtotal,
    const float* __restrict__ W1, const float* __restrict__ W2,
    unsigned short* __restrict__ Wf1, unsigned short* __restrict__ Wf2,
    int xblocks)
{
    if (blockIdx.x < (unsigned)xblocks) {
        int i = blockIdx.x * 256 + threadIdx.x;
        if (i >= xtotal) return;
        float4 v = x4[i];
        uint2 o;
        o.x = (unsigned)f2bf(v.x) | ((unsigned)f2bf(v.y) << 16);
        o.y = (unsigned)f2bf(v.z) | ((unsigned)f2bf(v.w) << 16);
        xh[i] = o;
    } else {
        int idx = (blockIdx.x - xblocks) * 256 + threadIdx.x;   // 0..32767
        const float* W = (idx < 16384) ? W1 : W2;
        unsigned short* Wf = (idx < 16384) ? Wf1 : Wf2;
        int e = idx & 16383;
        int j = e & 7, lane = (e >> 3) & 63, ckk = e >> 9;
        int ct = ckk & 7, kk = ckk >> 3;
        int k = kk * 32 + (lane >> 4) * 8 + j;
        int n = ct * 16 + (lane & 15);
        Wf[e] = f2bf(W[k * 128 + n]);
    }
}

// ---------------- bucket histogram (LDS-staged) ----------------
__global__ __launch_bounds__(256) void bucket_hist_kernel(
    const int* __restrict__ ei, int E, int NB, int* __restrict__ bucketCount)
{
    __shared__ int hist[512];
    int tid = threadIdx.x;
    for (int i = tid; i < NB; i += 256) hist[i] = 0;
    __syncthreads();
    int b0 = blockIdx.x * FB;
    int lim = min(FB, E - b0);
    for (int i = tid; i < lim; i += 256)
        atomicAdd(&hist[ei[E + b0 + i] >> 7], 1);
    __syncthreads();
    for (int i = tid; i < NB; i += 256)
        if (hist[i]) atomicAdd(&bucketCount[i], hist[i]);
}

// ---------------- bucket scan (1 block) ----------------
__global__ __launch_bounds__(512) void bucket_scan_kernel(
    const int* __restrict__ bucketCount, int NB, int E,
    int* __restrict__ bucketBase, int* __restrict__ bucketCursor)
{
    __shared__ int sm[512];
    int tid = threadIdx.x;
    int v = (tid < NB) ? bucketCount[tid] : 0;
    sm[tid] = v;
    __syncthreads();
    #pragma unroll
    for (int off = 1; off < 512; off <<= 1) {
        int u = (tid >= off) ? sm[tid - off] : 0;
        __syncthreads();
        sm[tid] += u;
        __syncthreads();
    }
    if (tid < NB) {
        int ex = sm[tid] - v;
        bucketBase[tid] = ex;
        bucketCursor[tid] = ex;
    }
    if (tid == 0) bucketBase[NB] = E;
}

// ---------------- bucket fill: rank in LDS, write contiguous runs ----------------
// rec[i] = (src << 7) | (dst & 127), grouped by bucket (dst >> 7)
__global__ __launch_bounds__(256) void bucket_fill_kernel(
    const int* __restrict__ ei, int E, int NB,
    int* __restrict__ bucketCursor, unsigned* __restrict__ rec)
{
    __shared__ int hist[512], base[512];
    int tid = threadIdx.x;
    int b0 = blockIdx.x * FB;
    for (int i = tid; i < NB; i += 256) hist[i] = 0;
    __syncthreads();
    int lim = min(FB, E - b0);
    for (int i = tid; i < lim; i += 256)
        atomicAdd(&hist[ei[E + b0 + i] >> 7], 1);
    __syncthreads();
    for (int i = tid; i < NB; i += 256) {
        int c = hist[i];
        base[i] = c ? atomicAdd(&bucketCursor[i], c) : 0;
        hist[i] = 0;   // reuse as rank counter
    }
    __syncthreads();
    for (int i = tid; i < lim; i += 256) {
        int e = b0 + i;
        int dst = ei[E + e], src = ei[e];
        int bk = dst >> 7;
        int r = atomicAdd(&hist[bk], 1);
        rec[base[bk] + r] = ((unsigned)src << 7) | (unsigned)(dst & 127);
    }
}

// ---------------- gather: LDS src-lists, 8 loads in flight, no chase ----------------
// block = (bucket, sub): handles dsts [bk*128 + sub*32, +32)
__global__ __launch_bounds__(256) void bucket_gather_kernel(
    const unsigned* __restrict__ xh, const unsigned* __restrict__ rec,
    const int* __restrict__ bucketBase, const float* __restrict__ epsp,
    unsigned* __restrict__ h0, int N, int zrow)
{
    int bk = blockIdx.x >> 2;
    int sub = blockIdx.x & 3;
    int tid = threadIdx.x;
    int d0 = (bk << 7) + (sub << 5);

    __shared__ int cnts[32], rnk[32], offs[33];
    __shared__ int slist[GCAP];

    if (tid < 32) { cnts[tid] = 0; rnk[tid] = 0; }
    __syncthreads();

    int lo = bucketBase[bk], hi = bucketBase[bk + 1];
    for (int i = lo + tid; i < hi; i += 256) {
        unsigned r = rec[i];
        int dl = r & 127;
        if ((dl >> 5) == sub) atomicAdd(&cnts[dl & 31], 1);
    }
    __syncthreads();
    if (tid == 0) {
        int run = 0;
        #pragma unroll
        for (int i = 0; i < 32; ++i) { offs[i] = run; run += cnts[i]; }
        offs[32] = run;
    }
    __syncthreads();
    for (int i = lo + tid; i < hi; i += 256) {
        unsigned r = rec[i];
        int dl = r & 127;
        if ((dl >> 5) == sub) {
            int d5 = dl & 31;
            int rk = atomicAdd(&rnk[d5], 1);
            int pos = offs[d5] + rk;
            if (pos < GCAP) slist[pos] = (int)(r >> 7);
        }
    }
    __syncthreads();

    int wv = tid >> 6, lane = tid & 63;
    float epsv = 1.0f + __ldg(epsp);
    #pragma unroll 1
    for (int j = 0; j < 8; ++j) {
        int d5 = wv * 8 + j;
        int d = d0 + d5;
        if (d >= N) break;
        int s = offs[d5], e = offs[d5 + 1];
        if (s > GCAP) s = GCAP;
        if (e > GCAP) e = GCAP;
        float2 xv = bfpair2f(xh[(size_t)d * 64 + lane]);
        float ax = epsv * xv.x, ay = epsv * xv.y;
        for (int i = s; i < e; i += 8) {
            #pragma unroll
            for (int k = 0; k < 8; ++k) {
                int idx = (i + k < e) ? slist[i + k] : zrow;   // zrow = zero row
                float2 v = bfpair2f(xh[(size_t)idx * 64 + lane]);
                ax += v.x; ay += v.y;
            }
        }
        h0[(size_t)d * 64 + lane] =
            (unsigned)f2bf(ax) | ((unsigned)f2bf(ay) << 16);
    }
}

// ---------------- MFMA GEMM + BN-stat accumulation (bf16 in/out) ----------------
// mode 0: A = a_bf rows as-is
// mode 1: A = bf16(relu(a_bf * s[k] + t[k])), s/t from stat_in + gamma/beta
__global__ __launch_bounds__(256) void gemm_bn_mfma_kernel(
    const unsigned short* __restrict__ a_bf,
    const float* __restrict__ stat_in, const float* __restrict__ gamma,
    const float* __restrict__ beta, float invN,
    const unsigned short* __restrict__ Wf, const float* __restrict__ bias,
    unsigned short* __restrict__ zout,
    float* __restrict__ stat_sum, float* __restrict__ stat_sq,
    int N, int mode)
{
    __shared__ unsigned short Wl[16384];   // 32 KB, fragment-ordered
    __shared__ float part[1024];
    __shared__ float scf[128], shf[128];

    int tid = threadIdx.x;
    {
        float4* dst = (float4*)Wl;
        const float4* srcp = (const float4*)Wf;
        #pragma unroll
        for (int i = 0; i < 8; ++i) dst[tid + i * 256] = srcp[tid + i * 256];
    }
    if (mode == 1 && tid < 128) {          // fused BN finalize for the input
        float mean = stat_in[tid] * invN;
        float var  = stat_in[128 + tid] * invN - mean * mean;
        float sv = gamma[tid] * rsqrtf(var + 1e-5f);
        scf[tid] = sv;
        shf[tid] = fmaf(-mean, sv, beta[tid]);
    }
    __syncthreads();

    int w = tid >> 6, lane = tid & 63, q = lane >> 4, n16 = lane & 15;
    int rowb = blockIdx.x * 64 + w * 16;
    int m = rowb + n16;
    int mc = (m < N) ? m : (N - 1);
    const unsigned short* arow = a_bf + (size_t)mc * D;

    f32x4 acc[8];
    #pragma unroll
    for (int ct = 0; ct < 8; ++ct) acc[ct] = (f32x4){0.f, 0.f, 0.f, 0.f};

    #pragma unroll
    for (int kk = 0; kk < 4; ++kk) {
        int c = kk * 32 + q * 8;
        short8 af;
        if (mode == 0) {
            af = *(const short8*)(arow + c);
        } else {
            uint4 rw = *(const uint4*)(arow + c);
            float2 p0 = bfpair2f(rw.x), p1 = bfpair2f(rw.y);
            float2 p2 = bfpair2f(rw.z), p3 = bfpair2f(rw.w);
            p0.x = fmaxf(fmaf(p0.x, scf[c + 0], shf[c + 0]), 0.f);
            p0.y = fmaxf(fmaf(p0.y, scf[c + 1], shf[c + 1]), 0.f);
            p1.x = fmaxf(fmaf(p1.x, scf[c + 2], shf[c + 2]), 0.f);
            p1.y = fmaxf(fmaf(p1.y, scf[c + 3], shf[c + 3]), 0.f);
            p2.x = fmaxf(fmaf(p2.x, scf[c + 4], shf[c + 4]), 0.f);
            p2.y = fmaxf(fmaf(p2.y, scf[c + 5], shf[c + 5]), 0.f);
            p3.x = fmaxf(fmaf(p3.x, scf[c + 6], shf[c + 6]), 0.f);
            p3.y = fmaxf(fmaf(p3.y, scf[c + 7], shf[c + 7]), 0.f);
            af[0] = (short)f2bf(p0.x); af[1] = (short)f2bf(p0.y);
            af[2] = (short)f2bf(p1.x); af[3] = (short)f2bf(p1.y);
            af[4] = (short)f2bf(p2.x); af[5] = (short)f2bf(p2.y);
            af[6] = (short)f2bf(p3.x); af[7] = (short)f2bf(p3.y);
        }
        #pragma unroll
        for (int ct = 0; ct < 8; ++ct) {
            short8 bf = *(const short8*)&Wl[(((kk * 8 + ct) * 64) + lane) * 8];
            acc[ct] = __builtin_amdgcn_mfma_f32_16x16x32_bf16(af, bf, acc[ct], 0, 0, 0);
        }
    }

    // epilogue: bias add, bf16 store, per-column stats (from fp32 values)
    #pragma unroll
    for (int ct = 0; ct < 8; ++ct) {
        int col = ct * 16 + n16;
        float bv = __ldg(bias + col);
        float s = 0.f, qs = 0.f;
        #pragma unroll
        for (int reg = 0; reg < 4; ++reg) {
            int row = rowb + q * 4 + reg;
            float v = acc[ct][reg] + bv;
            if (row < N) {
                zout[(size_t)row * D + col] = f2bf(v);
                s += v;
                qs = fmaf(v, v, qs);
            }
        }
        s  += __shfl_xor(s, 16, 64);
        s  += __shfl_xor(s, 32, 64);
        qs += __shfl_xor(qs, 16, 64);
        qs += __shfl_xor(qs, 32, 64);
        if (lane < 16) {
            part[w * 128 + col] = s;
            part[512 + w * 128 + col] = qs;
        }
    }
    __syncthreads();

    if (tid < 128) {
        float s  = part[tid] + part[128 + tid] + part[256 + tid] + part[384 + tid];
        float qq = part[512 + tid] + part[640 + tid] + part[768 + tid] + part[896 + tid];
        atomicAdd(&stat_sum[tid], s);
        atomicAdd(&stat_sq[tid], qq);
    }
}

// ------- final BN + ReLU (fused BN2 finalize): bf16 z2 -> fp32 out -------
__global__ __launch_bounds__(256) void bn_relu_kernel(
    const uint2* __restrict__ z2, float4* __restrict__ out,
    const float* __restrict__ stat2, const float* __restrict__ gamma,
    const float* __restrict__ beta, float invN, int total4)
{
    __shared__ float sf[128], tf[128];
    int tid = threadIdx.x;
    if (tid < 128) {
        float mean = stat2[tid] * invN;
        float var  = stat2[128 + tid] * invN - mean * mean;
        float sv = gamma[tid] * rsqrtf(var + 1e-5f);
        sf[tid] = sv;
        tf[tid] = fmaf(-mean, sv, beta[tid]);
    }
    __syncthreads();

    int i = blockIdx.x * 256 + tid;
    if (i >= total4) return;
    uint2 zp = z2[i];
    float2 v01 = bfpair2f(zp.x);
    float2 v23 = bfpair2f(zp.y);
    int c = (i & 31) * 4;
    float4 o;
    o.x = fmaxf(fmaf(v01.x, sf[c + 0], tf[c + 0]), 0.f);
    o.y = fmaxf(fmaf(v01.y, sf[c + 1], tf[c + 1]), 0.f);
    o.z = fmaxf(fmaf(v23.x, sf[c + 2], tf[c + 2]), 0.f);
    o.w = fmaxf(fmaf(v23.y, sf[c + 3], tf[c + 3]), 0.f);
    out[i] = o;
}

extern "C" void kernel_launch(void* const* d_in, const int* in_sizes, int n_in,
                              void* d_out, int out_size, void* d_ws, size_t ws_size,
                              hipStream_t stream)
{
    const float* x   = (const float*)d_in[0];
    const int*   ei  = (const int*)d_in[1];
    const float* eps = (const float*)d_in[2];
    const float* W1  = (const float*)d_in[3];
    const float* b1  = (const float*)d_in[4];
    const float* g1  = (const float*)d_in[5];
    const float* be1 = (const float*)d_in[6];
    const float* W2  = (const float*)d_in[7];
    const float* b2  = (const float*)d_in[8];
    const float* g2  = (const float*)d_in[9];
    const float* be2 = (const float*)d_in[10];

    int N = in_sizes[0] / D;       // 50000
    int E = in_sizes[1] / 2;       // 800000
    size_t ND = (size_t)N * D;
    int NB = (N + 127) >> 7;       // 391 buckets

    // workspace layout (~25.7 MB):
    //   xh: ND+128 ushorts (row N = zeros)      -> z1 reuses (phases 3+)
    //   region2: ND ushorts: rec (E unsigned)   -> z2 reuses (phases 4+)
    //   stats (512 f), bucketCount(512)/Base(513)/Cursor(512) ints, Wf1/Wf2
    unsigned short* xh  = (unsigned short*)d_ws;
    unsigned short* z1  = xh;
    unsigned short* region2 = xh + ND + 128;
    unsigned* rec       = (unsigned*)region2;
    unsigned short* z2  = region2;
    float* stats        = (float*)(region2 + ND);
    int* bucketCount    = (int*)(stats + 512);
    int* bucketBase     = bucketCount + 512;
    int* bucketCursor   = bucketBase + 513;
    unsigned short* Wf1 = (unsigned short*)(bucketCursor + 512);
    unsigned short* Wf2 = Wf1 + 16384;

    float* sum1 = stats + 0,   *sq1 = stats + 128;
    float* sum2 = stats + 256, *sq2 = stats + 384;
    unsigned short* h0 = (unsigned short*)d_out;

    hipMemsetAsync(stats, 0, 512 * sizeof(float), stream);
    hipMemsetAsync(bucketCount, 0, 512 * sizeof(int), stream);
    hipMemsetAsync(xh + ND, 0, 128 * sizeof(unsigned short), stream);  // zero row

    int xtotal = N * 32;                      // float4 groups in x
    int xblocks = (xtotal + 255) / 256;
    prep_kernel<<<xblocks + 128, 256, 0, stream>>>(
        (const float4*)x, (uint2*)xh, xtotal, W1, W2, Wf1, Wf2, xblocks);

    int fblocks = (E + FB - 1) / FB;
    bucket_hist_kernel<<<fblocks, 256, 0, stream>>>(ei, E, NB, bucketCount);
    bucket_scan_kernel<<<1, 512, 0, stream>>>(bucketCount, NB, E, bucketBase, bucketCursor);
    bucket_fill_kernel<<<fblocks, 256, 0, stream>>>(ei, E, NB, bucketCursor, rec);
    bucket_gather_kernel<<<NB * 4, 256, 0, stream>>>(
        (const unsigned*)xh, rec, bucketBase, eps, (unsigned*)h0, N, N);

    int gblocks = (N + 63) / 64;
    gemm_bn_mfma_kernel<<<gblocks, 256, 0, stream>>>(
        h0, nullptr, nullptr, nullptr, 0.f,
        Wf1, b1, z1, sum1, sq1, N, 0);
    gemm_bn_mfma_kernel<<<gblocks, 256, 0, stream>>>(
        z1, sum1, g1, be1, 1.0f / N,
        Wf2, b2, z2, sum2, sq2, N, 1);
    bn_relu_kernel<<<(N * 32 + 255) / 256, 256, 0, stream>>>(
        (const uint2*)z2, (float4*)d_out, sum2, g2, be2, 1.0f / N, N * 32);
}

// Round 10
// 228.715 us; speedup vs baseline: 1.2125x; 1.0121x over previous
//
#include <hip/hip_runtime.h>

#define D 128
#define FB 4096      // edges per hist/fill block
#define GCAP 1024    // src-list capacity per 32-dst gather block

typedef __attribute__((ext_vector_type(8))) short short8;
typedef __attribute__((ext_vector_type(4))) float f32x4;

static __device__ __forceinline__ unsigned short f2bf(float f) {
    union { float f; unsigned u; } v; v.f = f;
    unsigned r = v.u + 0x7FFF + ((v.u >> 16) & 1);   // RNE
    return (unsigned short)(r >> 16);
}

static __device__ __forceinline__ float2 bfpair2f(unsigned p) {
    union { unsigned u; float f; } a, b;
    a.u = (p & 0xFFFFu) << 16;
    b.u = p & 0xFFFF0000u;
    return make_float2(a.f, b.f);
}

// ------------- fused prep: x -> bf16 rows, W1/W2 -> bf16 fragments,
//               plus zero-init of stats / bucketCount / zero-row -------------
__global__ __launch_bounds__(256) void prep_kernel(
    const float4* __restrict__ x4, uint2* __restrict__ xh, int xtotal,
    const float* __restrict__ W1, const float* __restrict__ W2,
    unsigned short* __restrict__ Wf1, unsigned short* __restrict__ Wf2,
    float* __restrict__ stats, int* __restrict__ bucketCount,
    unsigned short* __restrict__ zrow, int xblocks)
{
    if (blockIdx.x < (unsigned)xblocks) {
        int i = blockIdx.x * 256 + threadIdx.x;
        if (i >= xtotal) return;
        float4 v = x4[i];
        uint2 o;
        o.x = (unsigned)f2bf(v.x) | ((unsigned)f2bf(v.y) << 16);
        o.y = (unsigned)f2bf(v.z) | ((unsigned)f2bf(v.w) << 16);
        xh[i] = o;
    } else if (blockIdx.x < (unsigned)(xblocks + 128)) {
        int idx = (blockIdx.x - xblocks) * 256 + threadIdx.x;   // 0..32767
        const float* W = (idx < 16384) ? W1 : W2;
        unsigned short* Wf = (idx < 16384) ? Wf1 : Wf2;
        int e = idx & 16383;
        int j = e & 7, lane = (e >> 3) & 63, ckk = e >> 9;
        int ct = ckk & 7, kk = ckk >> 3;
        int k = kk * 32 + (lane >> 4) * 8 + j;
        int n = ct * 16 + (lane & 15);
        Wf[e] = f2bf(W[k * 128 + n]);
    } else {
        int t = threadIdx.x;
        stats[t] = 0.f; stats[t + 256] = 0.f;
        bucketCount[t] = 0; bucketCount[t + 256] = 0;
        if (t < 128) zrow[t] = 0;
    }
}

// ---------------- bucket histogram (LDS-staged) ----------------
__global__ __launch_bounds__(256) void bucket_hist_kernel(
    const int* __restrict__ ei, int E, int NB, int* __restrict__ bucketCount)
{
    __shared__ int hist[512];
    int tid = threadIdx.x;
    for (int i = tid; i < NB; i += 256) hist[i] = 0;
    __syncthreads();
    int b0 = blockIdx.x * FB;
    int lim = min(FB, E - b0);
    for (int i = tid; i < lim; i += 256)
        atomicAdd(&hist[ei[E + b0 + i] >> 7], 1);
    __syncthreads();
    for (int i = tid; i < NB; i += 256)
        if (hist[i]) atomicAdd(&bucketCount[i], hist[i]);
}

// ---------------- bucket scan (1 block) ----------------
__global__ __launch_bounds__(512) void bucket_scan_kernel(
    const int* __restrict__ bucketCount, int NB, int E,
    int* __restrict__ bucketBase, int* __restrict__ bucketCursor)
{
    __shared__ int sm[512];
    int tid = threadIdx.x;
    int v = (tid < NB) ? bucketCount[tid] : 0;
    sm[tid] = v;
    __syncthreads();
    #pragma unroll
    for (int off = 1; off < 512; off <<= 1) {
        int u = (tid >= off) ? sm[tid - off] : 0;
        __syncthreads();
        sm[tid] += u;
        __syncthreads();
    }
    if (tid < NB) {
        int ex = sm[tid] - v;
        bucketBase[tid] = ex;
        bucketCursor[tid] = ex;
    }
    if (tid == 0) bucketBase[NB] = E;
}

// ---------------- bucket fill: rank in LDS, write contiguous runs ----------------
// rec[i] = (src << 7) | (dst & 127), grouped by bucket (dst >> 7)
__global__ __launch_bounds__(256) void bucket_fill_kernel(
    const int* __restrict__ ei, int E, int NB,
    int* __restrict__ bucketCursor, unsigned* __restrict__ rec)
{
    __shared__ int hist[512], base[512];
    int tid = threadIdx.x;
    int b0 = blockIdx.x * FB;
    for (int i = tid; i < NB; i += 256) hist[i] = 0;
    __syncthreads();
    int lim = min(FB, E - b0);
    for (int i = tid; i < lim; i += 256)
        atomicAdd(&hist[ei[E + b0 + i] >> 7], 1);
    __syncthreads();
    for (int i = tid; i < NB; i += 256) {
        int c = hist[i];
        base[i] = c ? atomicAdd(&bucketCursor[i], c) : 0;
        hist[i] = 0;   // reuse as rank counter
    }
    __syncthreads();
    for (int i = tid; i < lim; i += 256) {
        int e = b0 + i;
        int dst = ei[E + e], src = ei[e];
        int bk = dst >> 7;
        int r = atomicAdd(&hist[bk], 1);
        rec[base[bk] + r] = ((unsigned)src << 7) | (unsigned)(dst & 127);
    }
}

// ------- gather: LDS src-lists, dst-pairs with 16 loads in flight -------
// block = (bucket, sub): handles dsts [bk*128 + sub*32, +32)
__global__ __launch_bounds__(256) void bucket_gather_kernel(
    const unsigned* __restrict__ xh, const unsigned* __restrict__ rec,
    const int* __restrict__ bucketBase, const float* __restrict__ epsp,
    unsigned* __restrict__ h0, int N, int zrow)
{
    int bk = blockIdx.x >> 2;
    int sub = blockIdx.x & 3;
    int tid = threadIdx.x;
    int d0 = (bk << 7) + (sub << 5);

    __shared__ int cnts[32], rnk[32], offs[33];
    __shared__ int slist[GCAP];

    if (tid < 32) { cnts[tid] = 0; rnk[tid] = 0; }
    __syncthreads();

    int lo = bucketBase[bk], hi = bucketBase[bk + 1];
    for (int i = lo + tid; i < hi; i += 256) {
        unsigned r = rec[i];
        int dl = r & 127;
        if ((dl >> 5) == sub) atomicAdd(&cnts[dl & 31], 1);
    }
    __syncthreads();
    if (tid == 0) {
        int run = 0;
        #pragma unroll
        for (int i = 0; i < 32; ++i) { offs[i] = run; run += cnts[i]; }
        offs[32] = run;
    }
    __syncthreads();
    for (int i = lo + tid; i < hi; i += 256) {
        unsigned r = rec[i];
        int dl = r & 127;
        if ((dl >> 5) == sub) {
            int d5 = dl & 31;
            int rk = atomicAdd(&rnk[d5], 1);
            int pos = offs[d5] + rk;
            if (pos < GCAP) slist[pos] = (int)(r >> 7);
        }
    }
    __syncthreads();

    int wv = tid >> 6, lane = tid & 63;
    float epsv = 1.0f + __ldg(epsp);

    // 8 dsts per wave, processed in pairs -> 16 independent row loads in flight
    #pragma unroll 1
    for (int jj = 0; jj < 4; ++jj) {
        int dA = d0 + wv * 8 + jj * 2;
        int dB = dA + 1;
        int vA = (dA < N), vB = (dB < N);
        int iA = offs[(dA - d0)];
        int eA = offs[(dA - d0) + 1];
        int iB = vB ? offs[(dB - d0)] : 0;
        int eB = vB ? offs[(dB - d0) + 1] : 0;
        if (iA > GCAP) iA = GCAP;
        if (eA > GCAP) eA = GCAP;
        if (iB > GCAP) iB = GCAP;
        if (eB > GCAP) eB = GCAP;
        if (!vA) { iA = 0; eA = 0; }

        float2 xvA = bfpair2f(xh[(size_t)(vA ? dA : 0) * 64 + lane]);
        float2 xvB = bfpair2f(xh[(size_t)(vB ? dB : 0) * 64 + lane]);
        float axA = epsv * xvA.x, ayA = epsv * xvA.y;
        float axB = epsv * xvB.x, ayB = epsv * xvB.y;

        int iters = (eA - iA) > (eB - iB) ? (eA - iA) : (eB - iB);
        for (int it = 0; it < iters; it += 8) {
            unsigned pvA[8], pvB[8];
            #pragma unroll
            for (int k = 0; k < 8; ++k) {
                int idxA = (iA + k < eA) ? slist[iA + k] : zrow;
                int idxB = (iB + k < eB) ? slist[iB + k] : zrow;
                pvA[k] = xh[(size_t)idxA * 64 + lane];
                pvB[k] = xh[(size_t)idxB * 64 + lane];
            }
            #pragma unroll
            for (int k = 0; k < 8; ++k) {
                float2 a = bfpair2f(pvA[k]);
                float2 b = bfpair2f(pvB[k]);
                axA += a.x; ayA += a.y;
                axB += b.x; ayB += b.y;
            }
            iA += 8; iB += 8;
        }
        if (vA) h0[(size_t)dA * 64 + lane] =
            (unsigned)f2bf(axA) | ((unsigned)f2bf(ayA) << 16);
        if (vB) h0[(size_t)dB * 64 + lane] =
            (unsigned)f2bf(axB) | ((unsigned)f2bf(ayB) << 16);
    }
}

// ---------------- MFMA GEMM + BN-stat accumulation (bf16 in/out) ----------------
// mode 0: A = a_bf rows as-is
// mode 1: A = bf16(relu(a_bf * s[k] + t[k])), s/t from stat_in + gamma/beta
__global__ __launch_bounds__(256) void gemm_bn_mfma_kernel(
    const unsigned short* __restrict__ a_bf,
    const float* __restrict__ stat_in, const float* __restrict__ gamma,
    const float* __restrict__ beta, float invN,
    const unsigned short* __restrict__ Wf, const float* __restrict__ bias,
    unsigned short* __restrict__ zout,
    float* __restrict__ stat_sum, float* __restrict__ stat_sq,
    int N, int mode)
{
    __shared__ unsigned short Wl[16384];   // 32 KB, fragment-ordered
    __shared__ float part[1024];
    __shared__ float scf[128], shf[128];

    int tid = threadIdx.x;
    {
        float4* dst = (float4*)Wl;
        const float4* srcp = (const float4*)Wf;
        #pragma unroll
        for (int i = 0; i < 8; ++i) dst[tid + i * 256] = srcp[tid + i * 256];
    }
    if (mode == 1 && tid < 128) {          // fused BN finalize for the input
        float mean = stat_in[tid] * invN;
        float var  = stat_in[128 + tid] * invN - mean * mean;
        float sv = gamma[tid] * rsqrtf(var + 1e-5f);
        scf[tid] = sv;
        shf[tid] = fmaf(-mean, sv, beta[tid]);
    }
    __syncthreads();

    int w = tid >> 6, lane = tid & 63, q = lane >> 4, n16 = lane & 15;
    int rowb = blockIdx.x * 64 + w * 16;
    int m = rowb + n16;
    int mc = (m < N) ? m : (N - 1);
    const unsigned short* arow = a_bf + (size_t)mc * D;

    f32x4 acc[8];
    #pragma unroll
    for (int ct = 0; ct < 8; ++ct) acc[ct] = (f32x4){0.f, 0.f, 0.f, 0.f};

    #pragma unroll
    for (int kk = 0; kk < 4; ++kk) {
        int c = kk * 32 + q * 8;
        short8 af;
        if (mode == 0) {
            af = *(const short8*)(arow + c);
        } else {
            uint4 rw = *(const uint4*)(arow + c);
            float2 p0 = bfpair2f(rw.x), p1 = bfpair2f(rw.y);
            float2 p2 = bfpair2f(rw.z), p3 = bfpair2f(rw.w);
            p0.x = fmaxf(fmaf(p0.x, scf[c + 0], shf[c + 0]), 0.f);
            p0.y = fmaxf(fmaf(p0.y, scf[c + 1], shf[c + 1]), 0.f);
            p1.x = fmaxf(fmaf(p1.x, scf[c + 2], shf[c + 2]), 0.f);
            p1.y = fmaxf(fmaf(p1.y, scf[c + 3], shf[c + 3]), 0.f);
            p2.x = fmaxf(fmaf(p2.x, scf[c + 4], shf[c + 4]), 0.f);
            p2.y = fmaxf(fmaf(p2.y, scf[c + 5], shf[c + 5]), 0.f);
            p3.x = fmaxf(fmaf(p3.x, scf[c + 6], shf[c + 6]), 0.f);
            p3.y = fmaxf(fmaf(p3.y, scf[c + 7], shf[c + 7]), 0.f);
            af[0] = (short)f2bf(p0.x); af[1] = (short)f2bf(p0.y);
            af[2] = (short)f2bf(p1.x); af[3] = (short)f2bf(p1.y);
            af[4] = (short)f2bf(p2.x); af[5] = (short)f2bf(p2.y);
            af[6] = (short)f2bf(p3.x); af[7] = (short)f2bf(p3.y);
        }
        #pragma unroll
        for (int ct = 0; ct < 8; ++ct) {
            short8 bf = *(const short8*)&Wl[(((kk * 8 + ct) * 64) + lane) * 8];
            acc[ct] = __builtin_amdgcn_mfma_f32_16x16x32_bf16(af, bf, acc[ct], 0, 0, 0);
        }
    }

    // epilogue: bias add, bf16 store, per-column stats (from fp32 values)
    #pragma unroll
    for (int ct = 0; ct < 8; ++ct) {
        int col = ct * 16 + n16;
        float bv = __ldg(bias + col);
        float s = 0.f, qs = 0.f;
        #pragma unroll
        for (int reg = 0; reg < 4; ++reg) {
            int row = rowb + q * 4 + reg;
            float v = acc[ct][reg] + bv;
            if (row < N) {
                zout[(size_t)row * D + col] = f2bf(v);
                s += v;
                qs = fmaf(v, v, qs);
            }
        }
        s  += __shfl_xor(s, 16, 64);
        s  += __shfl_xor(s, 32, 64);
        qs += __shfl_xor(qs, 16, 64);
        qs += __shfl_xor(qs, 32, 64);
        if (lane < 16) {
            part[w * 128 + col] = s;
            part[512 + w * 128 + col] = qs;
        }
    }
    __syncthreads();

    if (tid < 128) {
        float s  = part[tid] + part[128 + tid] + part[256 + tid] + part[384 + tid];
        float qq = part[512 + tid] + part[640 + tid] + part[768 + tid] + part[896 + tid];
        atomicAdd(&stat_sum[tid], s);
        atomicAdd(&stat_sq[tid], qq);
    }
}

// ------- final BN + ReLU (fused BN2 finalize): bf16 z2 -> fp32 out -------
__global__ __launch_bounds__(256) void bn_relu_kernel(
    const uint2* __restrict__ z2, float4* __restrict__ out,
    const float* __restrict__ stat2, const float* __restrict__ gamma,
    const float* __restrict__ beta, float invN, int total4)
{
    __shared__ float sf[128], tf[128];
    int tid = threadIdx.x;
    if (tid < 128) {
        float mean = stat2[tid] * invN;
        float var  = stat2[128 + tid] * invN - mean * mean;
        float sv = gamma[tid] * rsqrtf(var + 1e-5f);
        sf[tid] = sv;
        tf[tid] = fmaf(-mean, sv, beta[tid]);
    }
    __syncthreads();

    int i = blockIdx.x * 256 + tid;
    if (i >= total4) return;
    uint2 zp = z2[i];
    float2 v01 = bfpair2f(zp.x);
    float2 v23 = bfpair2f(zp.y);
    int c = (i & 31) * 4;
    float4 o;
    o.x = fmaxf(fmaf(v01.x, sf[c + 0], tf[c + 0]), 0.f);
    o.y = fmaxf(fmaf(v01.y, sf[c + 1], tf[c + 1]), 0.f);
    o.z = fmaxf(fmaf(v23.x, sf[c + 2], tf[c + 2]), 0.f);
    o.w = fmaxf(fmaf(v23.y, sf[c + 3], tf[c + 3]), 0.f);
    out[i] = o;
}

extern "C" void kernel_launch(void* const* d_in, const int* in_sizes, int n_in,
                              void* d_out, int out_size, void* d_ws, size_t ws_size,
                              hipStream_t stream)
{
    const float* x   = (const float*)d_in[0];
    const int*   ei  = (const int*)d_in[1];
    const float* eps = (const float*)d_in[2];
    const float* W1  = (const float*)d_in[3];
    const float* b1  = (const float*)d_in[4];
    const float* g1  = (const float*)d_in[5];
    const float* be1 = (const float*)d_in[6];
    const float* W2  = (const float*)d_in[7];
    const float* b2  = (const float*)d_in[8];
    const float* g2  = (const float*)d_in[9];
    const float* be2 = (const float*)d_in[10];

    int N = in_sizes[0] / D;       // 50000
    int E = in_sizes[1] / 2;       // 800000
    size_t ND = (size_t)N * D;
    int NB = (N + 127) >> 7;       // 391 buckets

    // workspace layout (~25.7 MB):
    //   xh: ND+128 ushorts (row N = zeros)      -> z1 reuses (phases 3+)
    //   region2: ND ushorts: rec (E unsigned)   -> z2 reuses (phases 4+)
    //   stats (512 f), bucketCount(512)/Base(513)/Cursor(512) ints, Wf1/Wf2
    unsigned short* xh  = (unsigned short*)d_ws;
    unsigned short* z1  = xh;
    unsigned short* region2 = xh + ND + 128;
    unsigned* rec       = (unsigned*)region2;
    unsigned short* z2  = region2;
    float* stats        = (float*)(region2 + ND);
    int* bucketCount    = (int*)(stats + 512);
    int* bucketBase     = bucketCount + 512;
    int* bucketCursor   = bucketBase + 513;
    unsigned short* Wf1 = (unsigned short*)(bucketCursor + 512);
    unsigned short* Wf2 = Wf1 + 16384;

    float* sum1 = stats + 0,   *sq1 = stats + 128;
    float* sum2 = stats + 256, *sq2 = stats + 384;
    unsigned short* h0 = (unsigned short*)d_out;

    int xtotal = N * 32;                      // float4 groups in x
    int xblocks = (xtotal + 255) / 256;
    prep_kernel<<<xblocks + 129, 256, 0, stream>>>(
        (const float4*)x, (uint2*)xh, xtotal, W1, W2, Wf1, Wf2,
        stats, bucketCount, xh + ND, xblocks);

    int fblocks = (E + FB - 1) / FB;
    bucket_hist_kernel<<<fblocks, 256, 0, stream>>>(ei, E, NB, bucketCount);
    bucket_scan_kernel<<<1, 512, 0, stream>>>(bucketCount, NB, E, bucketBase, bucketCursor);
    bucket_fill_kernel<<<fblocks, 256, 0, stream>>>(ei, E, NB, bucketCursor, rec);
    bucket_gather_kernel<<<NB * 4, 256, 0, stream>>>(
        (const unsigned*)xh, rec, bucketBase, eps, (unsigned*)h0, N, N);

    int gblocks = (N + 63) / 64;
    gemm_bn_mfma_kernel<<<gblocks, 256, 0, stream>>>(
        h0, nullptr, nullptr, nullptr, 0.f,
        Wf1, b1, z1, sum1, sq1, N, 0);
    gemm_bn_mfma_kernel<<<gblocks, 256, 0, stream>>>(
        z1, sum1, g1, be1, 1.0f / N,
        Wf2, b2, z2, sum2, sq2, N, 1);
    bn_relu_kernel<<<(N * 32 + 255) / 256, 256, 0, stream>>>(
        (const uint2*)z2, (float4*)d_out, sum2, g2, be2, 1.0f / N, N * 32);
}